// Round 2
// baseline (535.202 us; speedup 1.0000x reference)
//
#include <hip/hip_runtime.h>
#include <stdint.h>

#define N_TOK 4096
#define DIM   256
#define NH    4
#define DH    64
#define TOPK  30
#define CANDN 40      // candidate margin: approx-top-40 superset of exact top-30
#define ATT_SCALE 0.25f
#define LN_EPS 1e-5f

typedef __attribute__((ext_vector_type(8))) short bf16x8;  // 8 bf16 in 4 VGPRs
typedef __attribute__((ext_vector_type(4))) float f32x4;

static __device__ __forceinline__ float bf2f(ushort u) {
    return __uint_as_float(((uint)u) << 16);
}
static __device__ __forceinline__ ushort f2bf(float f) {   // RNE
    uint x = __float_as_uint(f);
    return (ushort)((x + 0x7FFFu + ((x >> 16) & 1u)) >> 16);
}
static __device__ __forceinline__ bf16x8 load_frag(const ushort* p) {
    union { int4 i; bf16x8 f; } u;
    u.i = *reinterpret_cast<const int4*>(p);
    return u.f;
}
static __device__ __forceinline__ uint s16key(uint u) {    // bf16 bits -> sortable u16
    return (u & 0x8000u) ? (u ^ 0xFFFFu) : (u | 0x8000u);
}

// ---------------------------------------------------------------------------
// fp32 GEMM NT: C[i][j] = sum_d A[i][d]*W[j][d] + bias[j] (+ addX[i][j]).
// M=4096, N=256, K=256. Vector-ALU (no fp32 MFMA on CDNA4). Block: 256 thr,
// tile 64x64, each thread 4x4 outputs. Optional bf16 mirror output.
// ---------------------------------------------------------------------------
#define BK 32
__global__ __launch_bounds__(256) void proj_gemm_f32(
    const float* __restrict__ A, const float* __restrict__ W,
    const float* __restrict__ bias, const float* __restrict__ addX,
    float* __restrict__ outF, ushort* __restrict__ outB)
{
    __shared__ float As[BK][64 + 4];   // [k][i], +4 pad keeps 16B alignment
    __shared__ float Ws[BK][64 + 4];   // [k][j]
    const int tid = threadIdx.x;
    const int tx = tid & 15;           // col group (4 cols)
    const int ty = tid >> 4;           // row group (4 rows)
    const int i0 = blockIdx.y * 64;
    const int j0 = blockIdx.x * 64;

    float acc[4][4];
#pragma unroll
    for (int r = 0; r < 4; r++)
#pragma unroll
        for (int c = 0; c < 4; c++) acc[r][c] = 0.f;

    for (int k0 = 0; k0 < DIM; k0 += BK) {
#pragma unroll
        for (int u = 0; u < 2; u++) {
            const int f = u * 256 + tid;          // 0..511
            const int r = f >> 3;                 // row 0..63
            const int c = (f & 7) * 4;            // k offset 0,4..28
            float4 va = *reinterpret_cast<const float4*>(A + (size_t)(i0 + r) * DIM + k0 + c);
            As[c + 0][r] = va.x; As[c + 1][r] = va.y;
            As[c + 2][r] = va.z; As[c + 3][r] = va.w;
            float4 vw = *reinterpret_cast<const float4*>(W + (size_t)(j0 + r) * DIM + k0 + c);
            Ws[c + 0][r] = vw.x; Ws[c + 1][r] = vw.y;
            Ws[c + 2][r] = vw.z; Ws[c + 3][r] = vw.w;
        }
        __syncthreads();
#pragma unroll
        for (int kk = 0; kk < BK; kk++) {
            const float4 a4 = *reinterpret_cast<const float4*>(&As[kk][ty * 4]);
            const float4 b4 = *reinterpret_cast<const float4*>(&Ws[kk][tx * 4]);
            const float ar[4] = {a4.x, a4.y, a4.z, a4.w};
            const float br[4] = {b4.x, b4.y, b4.z, b4.w};
#pragma unroll
            for (int r = 0; r < 4; r++)
#pragma unroll
                for (int c = 0; c < 4; c++) acc[r][c] += ar[r] * br[c];
        }
        __syncthreads();
    }

#pragma unroll
    for (int r = 0; r < 4; r++) {
        const int gi = i0 + ty * 4 + r;
#pragma unroll
        for (int c = 0; c < 4; c++) {
            const int gj = j0 + tx * 4 + c;
            float v = acc[r][c] + bias[gj];
            if (addX) v += addX[(size_t)gi * DIM + gj];
            if (outF) outF[(size_t)gi * DIM + gj] = v;
            if (outB) outB[(size_t)gi * DIM + gj] = f2bf(v);
        }
    }
}

// ---------------------------------------------------------------------------
// Approx scores (bf16 q/k via MFMA, fp32 accum, stored bf16) into sb.
// Unscaled (scale>0 preserves ranking). wg 256 thr; BM=128 (wave 32 rows),
// BN=128, K=64 (one head slice).
// ---------------------------------------------------------------------------
__global__ __launch_bounds__(256) void scores_kernel(
    const ushort* __restrict__ qb, const ushort* __restrict__ kb,
    ushort* __restrict__ sb)
{
    const int lane = threadIdx.x & 63;
    const int wv   = threadIdx.x >> 6;
    const int h    = blockIdx.z;
    const int i0   = blockIdx.y * 128 + wv * 32;
    const int j0   = blockIdx.x * 128;
    const int r = lane & 15, q = lane >> 4;
    const int koff = h * DH;

    f32x4 acc[2][8];
#pragma unroll
    for (int a = 0; a < 2; a++)
#pragma unroll
        for (int b = 0; b < 8; b++) acc[a][b] = (f32x4){0.f, 0.f, 0.f, 0.f};

#pragma unroll
    for (int ks = 0; ks < 2; ks++) {
        const int kk = koff + ks * 32 + q * 8;
        bf16x8 af[2], bfr[8];
#pragma unroll
        for (int mt = 0; mt < 2; mt++)
            af[mt] = load_frag(qb + (size_t)(i0 + mt * 16 + r) * DIM + kk);
#pragma unroll
        for (int jt = 0; jt < 8; jt++)
            bfr[jt] = load_frag(kb + (size_t)(j0 + jt * 16 + r) * DIM + kk);
#pragma unroll
        for (int mt = 0; mt < 2; mt++)
#pragma unroll
            for (int jt = 0; jt < 8; jt++)
                acc[mt][jt] = __builtin_amdgcn_mfma_f32_16x16x32_bf16(
                    af[mt], bfr[jt], acc[mt][jt], 0, 0, 0);
    }

#pragma unroll
    for (int mt = 0; mt < 2; mt++)
#pragma unroll
        for (int rg = 0; rg < 4; rg++) {
            const int gi = i0 + mt * 16 + q * 4 + rg;   // C: row=(lane>>4)*4+reg
            ushort* row = sb + ((size_t)(h * N_TOK + gi)) * N_TOK;
#pragma unroll
            for (int jt = 0; jt < 8; jt++)
                row[j0 + jt * 16 + r] = f2bf(acc[mt][jt][rg]);  // col=lane&15
        }
}

// ---------------------------------------------------------------------------
// Per (h,i) row: read 4096 bf16 approx scores, binary-search rank-40
// threshold, compact candidates, exact fp32 rescore, bitonic sort (score
// desc, index asc), softmax over top-30 -> compact (idx,prob) + sparse ctx.
// One wave per row; 64 keys/lane.
// ---------------------------------------------------------------------------
__global__ __launch_bounds__(64) void select_kernel(
    const ushort* __restrict__ sb, const float* __restrict__ qf,
    const float* __restrict__ kf, const float* __restrict__ vf,
    float* __restrict__ pval, int* __restrict__ pidx,
    float* __restrict__ ctx)
{
    const int lane = threadIdx.x;
    const int i = blockIdx.x, h = blockIdx.y;
    const int row = h * N_TOK + i;
    const ushort* srow = sb + (size_t)row * N_TOK;

    __shared__ __align__(16) float qsh[DH];
    __shared__ uint  cand[64];
    __shared__ uint  ccnt;
    __shared__ float pw[TOPK];
    __shared__ int   jw[TOPK];

    qsh[lane] = qf[(size_t)i * DIM + h * DH + lane];
    if (lane == 0) ccnt = 0;

    uint key[64];
    const int4* srow4 = reinterpret_cast<const int4*>(srow);
#pragma unroll
    for (int t = 0; t < 8; t++) {
        int4 cc = srow4[t * 64 + lane];
        uint w[4] = {(uint)cc.x, (uint)cc.y, (uint)cc.z, (uint)cc.w};
#pragma unroll
        for (int wi = 0; wi < 4; wi++) {
            key[t * 8 + wi * 2 + 0] = s16key(w[wi] & 0xFFFFu);
            key[t * 8 + wi * 2 + 1] = s16key(w[wi] >> 16);
        }
    }

    // lo = max{T : count(key >= T) >= CANDN}
    uint lo = 0;
#pragma unroll
    for (int b = 15; b >= 0; b--) {
        uint trial = lo | (1u << b);
        int c = 0;
#pragma unroll
        for (int s = 0; s < 64; s++) c += (key[s] >= trial) ? 1 : 0;
#pragma unroll
        for (int off = 32; off; off >>= 1) c += __shfl_xor(c, off);
        if (c >= CANDN) lo = trial;
    }

    __syncthreads();

#pragma unroll
    for (int t = 0; t < 8; t++)
#pragma unroll
        for (int e = 0; e < 8; e++) {
            if (key[t * 8 + e] >= lo) {
                uint pos = atomicAdd(&ccnt, 1u);
                if (pos < 64u) cand[pos] = (uint)(t * 512 + lane * 8 + e);
            }
        }
    __syncthreads();
    const int m = (int)min(ccnt, 64u);

    unsigned long long ukey = 0ull;
    if (lane < m) {
        const int j = (int)cand[lane];
        const float4* kr = reinterpret_cast<const float4*>(kf + (size_t)j * DIM + h * DH);
        const float4* qr = reinterpret_cast<const float4*>(qsh);
        float s = 0.f;
#pragma unroll
        for (int d = 0; d < 16; d++) {
            float4 a = qr[d], bb = kr[d];
            s += a.x * bb.x; s += a.y * bb.y; s += a.z * bb.z; s += a.w * bb.w;
        }
        uint bits = __float_as_uint(s);
        uint s32 = (bits & 0x80000000u) ? ~bits : (bits | 0x80000000u);
        ukey = ((unsigned long long)s32 << 12) | (unsigned long long)(4095 - j);
    }

    // bitonic sort ascending (key: score, tie: smaller index wins)
#pragma unroll
    for (int k = 2; k <= 64; k <<= 1) {
#pragma unroll
        for (int jj = k >> 1; jj > 0; jj >>= 1) {
            unsigned long long o = __shfl_xor(ukey, jj);
            bool keepMax = ((lane & jj) != 0) ^ ((lane & k) != 0);
            ukey = keepMax ? (ukey > o ? ukey : o) : (ukey < o ? ukey : o);
        }
    }

    const int rank = 63 - lane;          // 0 = best
    const int jsel = 4095 - (int)(ukey & 0xFFFull);
    uint s32b = (uint)(ukey >> 12);
    uint fb = (s32b & 0x80000000u) ? (s32b ^ 0x80000000u) : ~s32b;
    const float sc = __uint_as_float(fb);
    const float stop = __shfl(sc, 63);   // max exact score (lane 63 is real: m>=40)

    float e = (rank < TOPK) ? __expf((sc - stop) * ATT_SCALE) : 0.f;
    float esum = e;
#pragma unroll
    for (int off = 32; off; off >>= 1) esum += __shfl_xor(esum, off);
    const float p = e / esum;

    if (rank < TOPK) {
        pw[rank] = p; jw[rank] = jsel;
        pval[(size_t)row * 32 + rank] = p;
        pidx[(size_t)row * 32 + rank] = jsel;
    }
    __syncthreads();

    float a = 0.f;
#pragma unroll
    for (int c = 0; c < TOPK; c++)
        a += pw[c] * vf[(size_t)jw[c] * DIM + h * DH + lane];
    ctx[(size_t)i * DIM + h * DH + lane] = a;
}

// ---------------------------------------------------------------------------
// Write final fp32 attn tensor: zero row + scatter 30 probs.
// ---------------------------------------------------------------------------
__global__ __launch_bounds__(256) void attn_write(
    const float* __restrict__ pval, const int* __restrict__ pidx,
    float* __restrict__ attnF)
{
    const int r = blockIdx.x;
    float* rowp = attnF + (size_t)r * N_TOK;
    float4* row4 = reinterpret_cast<float4*>(rowp);
    const float4 z = {0.f, 0.f, 0.f, 0.f};
#pragma unroll
    for (int t = 0; t < 4; t++) row4[t * 256 + threadIdx.x] = z;
    __syncthreads();   // compiler drains vmcnt before barrier -> zeros complete
    if (threadIdx.x < TOPK)
        rowp[pidx[(size_t)r * 32 + threadIdx.x]] = pval[(size_t)r * 32 + threadIdx.x];
}

// ---------------------------------------------------------------------------
// Row LayerNorm (biased var), in-place on fp32 resid. One wave per row.
// ---------------------------------------------------------------------------
__global__ __launch_bounds__(64) void ln_kernel(
    float* __restrict__ resb, const float* __restrict__ g,
    const float* __restrict__ b)
{
    const int i = blockIdx.x, lane = threadIdx.x;
    float4* rowp = reinterpret_cast<float4*>(resb + (size_t)i * DIM);
    float4 x = rowp[lane];
    float s  = x.x + x.y + x.z + x.w;
    float sq = x.x * x.x + x.y * x.y + x.z * x.z + x.w * x.w;
#pragma unroll
    for (int off = 32; off; off >>= 1) {
        s  += __shfl_xor(s, off);
        sq += __shfl_xor(sq, off);
    }
    const float mu  = s * (1.f / DIM);
    const float var = sq * (1.f / DIM) - mu * mu;
    const float rstd = rsqrtf(var + LN_EPS);
    const int col = lane * 4;
    float4 o;
    o.x = (x.x - mu) * rstd * g[col + 0] + b[col + 0];
    o.y = (x.y - mu) * rstd * g[col + 1] + b[col + 1];
    o.z = (x.z - mu) * rstd * g[col + 2] + b[col + 2];
    o.w = (x.w - mu) * rstd * g[col + 3] + b[col + 3];
    rowp[lane] = o;
}

// ---------------------------------------------------------------------------
extern "C" void kernel_launch(void* const* d_in, const int* in_sizes, int n_in,
                              void* d_out, int out_size, void* d_ws, size_t ws_size,
                              hipStream_t stream)
{
    const float* key_in   = (const float*)d_in[0];
    const float* value_in = (const float*)d_in[1];
    const float* query_in = (const float*)d_in[2];
    const float* Wq = (const float*)d_in[3];
    const float* bq = (const float*)d_in[4];
    const float* Wk = (const float*)d_in[5];
    const float* bk = (const float*)d_in[6];
    const float* Wv = (const float*)d_in[7];
    const float* bv = (const float*)d_in[8];
    const float* Wo = (const float*)d_in[9];
    const float* bo = (const float*)d_in[10];
    const float* ln_g = (const float*)d_in[11];
    const float* ln_b = (const float*)d_in[12];

    float* outF  = (float*)d_out;                     // (N, D) fp32, 1M floats
    float* attnF = outF + (size_t)N_TOK * DIM;        // (H, N, N) fp32, 67.1M floats

    // Large scratch carved inside the attn output region (consumed before
    // attn_write overwrites it). Float offsets relative to attnF:
    //   [0, 33.55M)       bf16 approx scores sb (67.1M ushorts)
    //   [33.55M, +1M)     qf   fp32
    //   [+1M, +2M)        kf   fp32
    //   [+2M, +3M)        vf   fp32
    //   [+3M, +3.5M)      qb   bf16 (1M ushorts)
    //   [+3.5M, +4M)      kb   bf16
    //   [+4M, +5M)        ctx  fp32
    const size_t SC = 33554432;               // 2 ushorts per attn float slot
    ushort* sb  = (ushort*)attnF;
    float*  qf  = attnF + SC;
    float*  kf  = attnF + SC + 1048576;
    float*  vf  = attnF + SC + 2097152;
    ushort* qb  = (ushort*)(attnF + SC + 3145728);
    ushort* kb  = (ushort*)(attnF + SC + 3670016);
    float*  ctx = attnF + SC + 4194304;

    float* pval = (float*)d_ws;               // 16384 * 32 fp32 (2 MB)
    int*   pidx = (int*)d_ws + 524288;        // 16384 * 32 int  (2 MB)

    const dim3 gP(4, 64), bP(256);
    proj_gemm_f32<<<gP, bP, 0, stream>>>(query_in, Wq, bq, nullptr, qf, qb);
    proj_gemm_f32<<<gP, bP, 0, stream>>>(key_in,   Wk, bk, nullptr, kf, kb);
    proj_gemm_f32<<<gP, bP, 0, stream>>>(value_in, Wv, bv, nullptr, vf, nullptr);

    scores_kernel<<<dim3(32, 32, NH), 256, 0, stream>>>(qb, kb, sb);
    select_kernel<<<dim3(N_TOK, NH), 64, 0, stream>>>(sb, qf, kf, vf, pval, pidx, ctx);

    proj_gemm_f32<<<gP, bP, 0, stream>>>(ctx, Wo, bo, query_in, outF, nullptr);
    ln_kernel<<<N_TOK, 64, 0, stream>>>(outF, ln_g, ln_b);

    attn_write<<<N_TOK * NH, 256, 0, stream>>>(pval, pidx, attnF);
}